// Round 16
// baseline (130.948 us; speedup 1.0000x reference)
//
#include <hip/hip_runtime.h>
#include <stdint.h>

// Scaled-dot-product attention. B=4, NQ=NK=4096, D=128, fp32 in/out.
// R17: split-K across 2 blocks. R16 decomposition: overhead 55.6 + attn 48.7
// + prep 10; attn is sync/latency-bound at 2 waves/SIMD with both pipes ~40%
// idle. R11/R13 occupancy attacks failed via traffic/register taxes; this one
// pays neither: the R14 block (512thr, 128 VGPR, 71KB LDS — already shaped
// for 2 blocks/CU) is kept verbatim, but 512 blocks each process HALF the
// key range. Two INDEPENDENT blocks per CU: one block's barrier stall hides
// under the other's MFMA. No-max softmax makes partials exactly additive
// (O=O1+O2, l=l1+l2): blocks write unnormalized O + l to ws; a combine
// kernel normalizes (~24MB, ~4-5us). Q scale folded into bf16 conversion.
#define B_ 4
#define NQ_ 4096
#define NK_ 4096
#define D_ 128
#define BM_ 64
#define BN_ 128
#define NITER_ (NK_/BN_)
#define NSPLIT_ 2
#define NITH_ (NITER_/NSPLIT_)   // 16 tiles per block
#define PS_ 136        // P row stride (shorts): 272 B
#define OS_ 66         // epilogue O region row stride (floats)

typedef __attribute__((ext_vector_type(8))) short short8;
typedef __attribute__((ext_vector_type(4))) float floatx4;
typedef unsigned int u32;

union frag_u { u32 u[4]; short8 s; };
union pair_u { u32 u[2]; uint2 v; };

__device__ __forceinline__ unsigned short f2bf_rne(float x){
  union { float f; u32 u; } c; c.f = x;
  u32 u = c.u;
  return (unsigned short)((u + 0x7fffu + ((u >> 16) & 1u)) >> 16);
}
// pack 2 f32 -> 2 bf16 (round-half-up; bias << bf16 quantization)
__device__ __forceinline__ u32 pk2bf(float a, float b){
  union { float f; u32 u; } x, y; x.f = a; y.f = b;
  return ((x.u + 0x8000u) >> 16) | ((y.u + 0x8000u) & 0xffff0000u);
}

// ---- prep (R16) ----
// Fragment layouts:
//  Kf chunk flat = (((b*32+it)*8 + wq)*4 + j)*64 + lane : 8 shorts =
//     K[b][it*128 + kg*32 + (l15>>2)*8 + dh*4 + (l15&3)][j*32 + l4*8 .. +8]
//  Vf chunk flat = (((b*32+it)*8 + wq)*4 + dt)*64 + lane : short kk(0..7) =
//     V[b][it*128 + kg*32 + l4*8 + kk][dh*64 + dt*16 + l15]   (wq = kg*2+dh)
__global__ __launch_bounds__(256) void prep_kernel(
    const float* __restrict__ k, const float* __restrict__ v,
    unsigned short* __restrict__ kf, unsigned short* __restrict__ vf){
  __shared__ __align__(16) char smem[40960];
  const int t = threadIdx.x;
  const int blk = blockIdx.x;
  if (blk < 128){
    // ---------------- K part ----------------
    int b = blk >> 5, it = blk & 31;
    const float* src = k + ((size_t)b*NK_ + it*BN_)*D_;
    #pragma unroll
    for (int i = 0; i < 16; i++){
      int f = t + i*256;                 // 0..4095 float4s
      int row = f >> 5, c4 = f & 31;     // row = local key, c4*4 = d
      float4 a = *(const float4*)(src + (size_t)row*D_ + c4*4);
      ushort4 s;
      s.x = f2bf_rne(a.x); s.y = f2bf_rne(a.y);
      s.z = f2bf_rne(a.z); s.w = f2bf_rne(a.w);
      int kg = row >> 5, rem = row & 31;
      int dh = (rem >> 2) & 1;
      int l15 = ((rem >> 3) << 2) | (rem & 3);
      int wq = kg*2 + dh;
      int j = c4 >> 3, l4 = (c4 >> 1) & 3, half = c4 & 1;
      *(ushort4*)(smem + (wq*4 + j)*1088 + l4*272 + l15*16 + half*8) = s;
    }
    __syncthreads();
    unsigned short* dst = kf + (size_t)(b*32 + it)*2048*8;
    #pragma unroll
    for (int i = 0; i < 8; i++){
      int c = t + i*256;                 // 0..2047 chunks
      int lane = c & 63, j = (c >> 6) & 3, wq = c >> 8;
      int l15 = lane & 15, l4 = lane >> 4;
      short8 x = *(const short8*)(smem + (wq*4 + j)*1088 + l4*272 + l15*16);
      *(short8*)(dst + (size_t)c*8) = x;
    }
  } else {
    // ---------------- V part (paired-row b32 writes) ----------------
    int blk2 = blk - 128;
    int b = blk2 >> 5, it = blk2 & 31;
    const float* src = v + ((size_t)b*NK_ + it*BN_)*D_;
    #pragma unroll
    for (int i = 0; i < 8; i++){
      int u2 = t + i*256;                // 0..2047 (row-pair, c4) items
      int rp = u2 >> 5, c4 = u2 & 31;    // rp = 0..63, c4*4 = d
      int r0 = rp*2;                     // rows r0, r0+1 share kga/l4a; kk0 even
      const float* p0r = src + (size_t)r0*D_ + c4*4;
      float4 a0 = *(const float4*)p0r;
      float4 a1 = *(const float4*)(p0r + D_);
      int kk0 = r0 & 7;
      int l4a = (r0 >> 3) & 3, kga = r0 >> 5;
      float v0[4] = {a0.x, a0.y, a0.z, a0.w};
      float v1[4] = {a1.x, a1.y, a1.z, a1.w};
      #pragma unroll
      for (int jj = 0; jj < 4; jj++){
        int d = c4*4 + jj;
        int dh = d >> 6, dt = (d >> 4) & 3, l15 = d & 15;
        int c = ((kga*2 + dh)*4 + dt)*64 + l4a*16 + l15;
        ushort2 s2; s2.x = f2bf_rne(v0[jj]); s2.y = f2bf_rne(v1[jj]);
        *(ushort2*)(smem + c*16 + (c>>2)*16 + kk0*2) = s2;
      }
    }
    __syncthreads();
    unsigned short* dst = vf + (size_t)(b*32 + it)*2048*8;
    #pragma unroll
    for (int i = 0; i < 8; i++){
      int c = t + i*256;
      short8 x = *(const short8*)(smem + c*16 + (c>>2)*16);
      *(short8*)(dst + (size_t)c*8) = x;
    }
  }
}

// ---- main kernel (R14 body; half the key range per block) ----
// grid 512: bit0,bits4-8 = qt; bits1-2 = b (XCD-constant, both halves of a
// batch on that batch's XCD pair); bit3 = key-half. block 512 = 8 waves =
// (kg:4) x (dh:2). Round r: S(2r)->bufA, S(2r+1)->bufB, one raw barrier,
// PV(2r), PV(2r+1). Writes UNNORMALIZED partial O + partial l to workspace.
__global__ __launch_bounds__(512, 2) void attn_kernel(
    const float* __restrict__ Qf, const unsigned short* __restrict__ Kb,
    const unsigned short* __restrict__ Vt,
    float* __restrict__ Op, float* __restrict__ Lp){
  __shared__ __align__(16) char sm[71680];
  unsigned short* smP = (unsigned short*)sm;      // 4 x 64 x PS_ shorts = 69632 B
  float* smO = (float*)sm;                        // epilogue alias: 4 x 64 x OS_ floats
  float* smL = (float*)(sm + 69632);              // 8 x 64 f32 = 2048 B

  const int bi = blockIdx.x;
  const int b    = (bi >> 1) & 3;               // batch constant per XCD-pair
  const int half = (bi >> 3) & 1;               // key-range half
  const int qt   = ((bi >> 4) << 1) | (bi & 1); // 0..63
  const int q0 = qt * BM_;
  const int tid = threadIdx.x;
  const int w = tid >> 6, lane = tid & 63;
  const int kg = w >> 1, dh = w & 1;
  const int l15 = lane & 15, l4 = lane >> 4;

  const short8* Kfrag = (const short8*)Kb;
  const short8* Vfrag = (const short8*)Vt;
  const size_t FSTRIDE = 8*4*64;                 // short8 units per K-tile iter
  const size_t fbase = (((size_t)b*32)*8 + w)*4*64 + lane;
  const int hbase = half * NITH_;

  // ---- Q fragments direct from fp32 global (scale folded into conversion) ----
  const float SL = 0.08838834764831845f * 1.4426950408889634f; // 1/sqrt(128)*log2(e)
  short8 qf[4][4];
  {
    const float* qp = Qf + ((size_t)b*NQ_ + q0)*D_;
    #pragma unroll
    for (int nb = 0; nb < 4; nb++)
      #pragma unroll
      for (int kbq = 0; kbq < 4; kbq++){
        const float* p = qp + (size_t)(nb*16 + l15)*D_ + kbq*32 + l4*8;
        float4 a = *(const float4*)p;
        float4 c4 = *(const float4*)(p + 4);
        frag_u f;
        f.u[0] = pk2bf(a.x*SL, a.y*SL);   f.u[1] = pk2bf(a.z*SL, a.w*SL);
        f.u[2] = pk2bf(c4.x*SL, c4.y*SL); f.u[3] = pk2bf(c4.z*SL, c4.w*SL);
        qf[nb][kbq] = f.s;
      }
  }

  // ---- prologue: A set <- tile hbase, B set <- tile hbase+1 ----
  short8 kfA[4], kfB[4], vfA[4], vfB[4];
  #pragma unroll
  for (int j = 0; j < 4; j++) kfA[j] = Kfrag[fbase + (size_t)hbase*FSTRIDE + j*64];
  #pragma unroll
  for (int dt = 0; dt < 4; dt++) vfA[dt] = Vfrag[fbase + (size_t)hbase*FSTRIDE + dt*64];
  #pragma unroll
  for (int j = 0; j < 4; j++) kfB[j] = Kfrag[fbase + (size_t)(hbase+1)*FSTRIDE + j*64];
  #pragma unroll
  for (int dt = 0; dt < 4; dt++) vfB[dt] = Vfrag[fbase + (size_t)(hbase+1)*FSTRIDE + dt*64];

  floatx4 o[4][4];
  #pragma unroll
  for (int nb = 0; nb < 4; nb++)
    #pragma unroll
    for (int dt = 0; dt < 4; dt++) o[nb][dt] = (floatx4)0.0f;
  float lsum[4] = {0.f, 0.f, 0.f, 0.f};

  const size_t prow = (size_t)kg*32 + l4*8;

  for (int r = 0; r < NITH_/2; ++r){
    const int lt = 2*r;                 // local tile within this half
    const int it = hbase + lt;          // global tile
    unsigned short* bufA = smP + (size_t)(r & 1) * (2*64*PS_);
    unsigned short* bufB = bufA + 64*PS_;

    // ---- S(A): tile it -> bufA ----
    {
      floatx4 s[4];
      #pragma unroll
      for (int nb = 0; nb < 4; nb++){
        s[nb] = (floatx4)0.0f;
        s[nb] = __builtin_amdgcn_mfma_f32_16x16x32_bf16(kfA[0], qf[nb][0], s[nb], 0,0,0);
        s[nb] = __builtin_amdgcn_mfma_f32_16x16x32_bf16(kfA[1], qf[nb][1], s[nb], 0,0,0);
        s[nb] = __builtin_amdgcn_mfma_f32_16x16x32_bf16(kfA[2], qf[nb][2], s[nb], 0,0,0);
        s[nb] = __builtin_amdgcn_mfma_f32_16x16x32_bf16(kfA[3], qf[nb][3], s[nb], 0,0,0);
      }
      // prefetch K(it+2) -> A (kfA dead after S)
      if (lt + 2 < NITH_){
        #pragma unroll
        for (int j = 0; j < 4; j++)
          kfA[j] = Kfrag[fbase + (size_t)(it+2)*FSTRIDE + j*64];
      }
      #pragma unroll
      for (int nb = 0; nb < 4; nb++){
        float p0 = __builtin_amdgcn_exp2f(s[nb][0]);
        float p1 = __builtin_amdgcn_exp2f(s[nb][1]);
        float p2 = __builtin_amdgcn_exp2f(s[nb][2]);
        float p3 = __builtin_amdgcn_exp2f(s[nb][3]);
        lsum[nb] += (p0 + p1) + (p2 + p3);
        pair_u pp; pp.u[0] = pk2bf(p0, p1); pp.u[1] = pk2bf(p2, p3);
        *(uint2*)(bufA + (size_t)(nb*16 + l15)*PS_ + prow + dh*4) = pp.v;
      }
    }
    // ---- S(B): tile it+1 -> bufB ----
    {
      floatx4 s[4];
      #pragma unroll
      for (int nb = 0; nb < 4; nb++){
        s[nb] = (floatx4)0.0f;
        s[nb] = __builtin_amdgcn_mfma_f32_16x16x32_bf16(kfB[0], qf[nb][0], s[nb], 0,0,0);
        s[nb] = __builtin_amdgcn_mfma_f32_16x16x32_bf16(kfB[1], qf[nb][1], s[nb], 0,0,0);
        s[nb] = __builtin_amdgcn_mfma_f32_16x16x32_bf16(kfB[2], qf[nb][2], s[nb], 0,0,0);
        s[nb] = __builtin_amdgcn_mfma_f32_16x16x32_bf16(kfB[3], qf[nb][3], s[nb], 0,0,0);
      }
      // prefetch K(it+3) -> B (kfB dead after S)
      if (lt + 3 < NITH_){
        #pragma unroll
        for (int j = 0; j < 4; j++)
          kfB[j] = Kfrag[fbase + (size_t)(it+3)*FSTRIDE + j*64];
      }
      #pragma unroll
      for (int nb = 0; nb < 4; nb++){
        float p0 = __builtin_amdgcn_exp2f(s[nb][0]);
        float p1 = __builtin_amdgcn_exp2f(s[nb][1]);
        float p2 = __builtin_amdgcn_exp2f(s[nb][2]);
        float p3 = __builtin_amdgcn_exp2f(s[nb][3]);
        lsum[nb] += (p0 + p1) + (p2 + p3);
        pair_u pp; pp.u[0] = pk2bf(p0, p1); pp.u[1] = pk2bf(p2, p3);
        *(uint2*)(bufB + (size_t)(nb*16 + l15)*PS_ + prow + dh*4) = pp.v;
      }
    }

    // ---- ONE barrier for both tiles ----
    asm volatile("s_waitcnt lgkmcnt(0)" ::: "memory");
    __builtin_amdgcn_s_barrier();
    asm volatile("" ::: "memory");

    // ---- PV(A): tile it ----
    {
      short8 pf[4];
      #pragma unroll
      for (int nb = 0; nb < 4; nb++)
        pf[nb] = *(const short8*)(bufA + (size_t)(nb*16 + l15)*PS_ + prow);
      #pragma unroll
      for (int nb = 0; nb < 4; nb++)
        #pragma unroll
        for (int dt = 0; dt < 4; dt++)
          o[nb][dt] = __builtin_amdgcn_mfma_f32_16x16x32_bf16(pf[nb], vfA[dt], o[nb][dt], 0,0,0);
      // prefetch V(it+2) -> A (vfA dead after PV)
      if (lt + 2 < NITH_){
        #pragma unroll
        for (int dt = 0; dt < 4; dt++)
          vfA[dt] = Vfrag[fbase + (size_t)(it+2)*FSTRIDE + dt*64];
      }
    }
    // ---- PV(B): tile it+1 ----
    {
      short8 pf[4];
      #pragma unroll
      for (int nb = 0; nb < 4; nb++)
        pf[nb] = *(const short8*)(bufB + (size_t)(nb*16 + l15)*PS_ + prow);
      #pragma unroll
      for (int nb = 0; nb < 4; nb++)
        #pragma unroll
        for (int dt = 0; dt < 4; dt++)
          o[nb][dt] = __builtin_amdgcn_mfma_f32_16x16x32_bf16(pf[nb], vfB[dt], o[nb][dt], 0,0,0);
      // prefetch V(it+3) -> B (vfB dead after PV)
      if (lt + 3 < NITH_){
        #pragma unroll
        for (int dt = 0; dt < 4; dt++)
          vfB[dt] = Vfrag[fbase + (size_t)(it+3)*FSTRIDE + dt*64];
      }
    }
    // next round writes the OTHER buffer pair; this pair's reuse (round r+2)
    // is fenced by the barrier at round r+1.
  }

  // ---- epilogue: l reduce, O reduce over 4 key-groups, write PARTIALS ----
  #pragma unroll
  for (int nb = 0; nb < 4; nb++){
    float v = lsum[nb];
    v += __shfl_xor(v, 16);
    v += __shfl_xor(v, 32);
    lsum[nb] = v;
  }
  if (l4 == 0)
    #pragma unroll
    for (int nb = 0; nb < 4; nb++)
      smL[w*64 + nb*16 + l15] = lsum[nb];

  __syncthreads();   // all last-round P reads done before smO aliases the P region

  if (w >= 4){
    float* r = smO + (size_t)(w - 4) * 4224;
    #pragma unroll
    for (int nb = 0; nb < 4; nb++)
      #pragma unroll
      for (int dt = 0; dt < 4; dt++)
        #pragma unroll
        for (int q = 0; q < 4; q++)
          r[(size_t)(nb*16 + l4*4 + q)*OS_ + dt*16 + l15] = o[nb][dt][q];
  }
  __syncthreads();
  if (w < 4){
    float* r = smO + (size_t)w * 4224;
    #pragma unroll
    for (int nb = 0; nb < 4; nb++)
      #pragma unroll
      for (int dt = 0; dt < 4; dt++)
        #pragma unroll
        for (int q = 0; q < 4; q++)
          o[nb][dt][q] += r[(size_t)(nb*16 + l4*4 + q)*OS_ + dt*16 + l15];
  }
  __syncthreads();
  if (w == 2 || w == 3){
    float* r = smO + (size_t)(w - 2) * 4224;
    #pragma unroll
    for (int nb = 0; nb < 4; nb++)
      #pragma unroll
      for (int dt = 0; dt < 4; dt++)
        #pragma unroll
        for (int q = 0; q < 4; q++)
          r[(size_t)(nb*16 + l4*4 + q)*OS_ + dt*16 + l15] = o[nb][dt][q];
  }
  __syncthreads();
  if (w < 2){
    float* r = smO + (size_t)w * 4224;
    float* og = Op + (((size_t)half*B_ + b)*NQ_ + q0)*D_ + dh*64;
    float* lg = Lp + ((size_t)half*B_ + b)*NQ_ + q0;
    #pragma unroll
    for (int nb = 0; nb < 4; nb++)
      #pragma unroll
      for (int q = 0; q < 4; q++){
        int row = nb*16 + l4*4 + q;
        float lt = 0.f;
        #pragma unroll
        for (int w2 = 0; w2 < 8; w2++) lt += smL[w2*64 + row];
        if (dh == 0 && l15 == 0) lg[row] = lt;
        #pragma unroll
        for (int dt = 0; dt < 4; dt++)
          og[(size_t)row*D_ + dt*16 + l15] = o[nb][dt][q] + r[(size_t)row*OS_ + dt*16 + l15];
      }
  }
}

// ---- combine: Out = (Op0 + Op1) / (Lp0 + Lp1) ----
// 524288 float4s total; grid 2048 x 256, one float4 per thread.
__global__ __launch_bounds__(256) void combine_kernel(
    const float* __restrict__ Op, const float* __restrict__ Lp,
    float* __restrict__ Out){
  int f = blockIdx.x * 256 + threadIdx.x;        // float4 index
  size_t row = ((size_t)f * 4) / D_;             // 0 .. B*NQ-1
  float4 a = ((const float4*)Op)[f];
  float4 c = ((const float4*)(Op + (size_t)B_*NQ_*D_))[f];
  float l = Lp[row] + Lp[(size_t)B_*NQ_ + row];
  float inv = 1.0f / l;
  float4 o;
  o.x = (a.x + c.x) * inv; o.y = (a.y + c.y) * inv;
  o.z = (a.z + c.z) * inv; o.w = (a.w + c.w) * inv;
  ((float4*)Out)[f] = o;
}

extern "C" void kernel_launch(void* const* d_in, const int* in_sizes, int n_in,
                              void* d_out, int out_size, void* d_ws, size_t ws_size,
                              hipStream_t stream){
  const float* q = (const float*)d_in[0];   // target [4,4096,128]
  const float* k = (const float*)d_in[1];   // key    [4,4096,128]
  const float* v = (const float*)d_in[2];   // value  [4,4096,128]
  float* out = (float*)d_out;
  unsigned short* kb = (unsigned short*)d_ws;          // K frag-major bf16, 4 MiB
  unsigned short* vt = kb + (size_t)B_*NK_*D_;         // V frag-major bf16, 4 MiB
  float* Op = (float*)((char*)d_ws + (size_t)8*1024*1024);   // 2 x 8 MiB partial O
  float* Lp = (float*)((char*)d_ws + (size_t)24*1024*1024);  // 2 x 64 KiB partial l
  prep_kernel<<<256, 256, 0, stream>>>(k, v, kb, vt);
  attn_kernel<<<512, 512, 0, stream>>>(q, kb, vt, Op, Lp);
  combine_kernel<<<2048, 256, 0, stream>>>(Op, Lp, out);
}